// Round 2
// baseline (75.436 us; speedup 1.0000x reference)
//
#include <hip/hip_runtime.h>

#define BSZ 512
#define NN  500
#define KK  100
#define SS  96
#define HIDN 32

// ---------------- kernel 1: exclusive prefix sum of idx_of_node ----------------
__global__ __launch_bounds__(BSZ) void offs_kernel(const int* __restrict__ idx_of_node,
                                                   int* __restrict__ offs) {
    __shared__ int buf[BSZ];
    int t = threadIdx.x;
    int v = idx_of_node[t];
    buf[t] = v;
    __syncthreads();
    int acc = v;
    for (int d = 1; d < BSZ; d <<= 1) {
        int add = (t >= d) ? buf[t - d] : 0;
        __syncthreads();
        acc += add;
        buf[t] = acc;
        __syncthreads();
    }
    offs[t] = acc - v;  // exclusive prefix
}

// ---------------- kernel 2: gather -> MLP -> gate -> masked scatter ----------------
// 64-thread blocks: 800 blocks, ~3/CU. Latency-bound -> keep y-row in registers
// (fully unrolled, static indices) to avoid a second dependent global read.
__global__ __launch_bounds__(64) void scatter_kernel(
    const float* __restrict__ y, const float* __restrict__ W1,
    const float* __restrict__ b1, const float* __restrict__ W2,
    const float* __restrict__ b2, const float* __restrict__ mask,
    const float* __restrict__ gumbel, const int* __restrict__ krig_idx,
    const int* __restrict__ offs, float* __restrict__ out) {
    __shared__ float4 w1s[SS * HIDN / 4];  // 12 KB, row-major [s][j]
    __shared__ float b1s[HIDN];
    __shared__ float w2s[HIDN * 2];
    __shared__ float b2s[2];
    for (int i = threadIdx.x; i < SS * HIDN / 4; i += 64)
        w1s[i] = reinterpret_cast<const float4*>(W1)[i];
    if (threadIdx.x < HIDN) {
        b1s[threadIdx.x] = b1[threadIdx.x];
        w2s[threadIdx.x] = W2[threadIdx.x];
        w2s[threadIdx.x + HIDN] = W2[threadIdx.x + HIDN];
    }
    if (threadIdx.x < 2) b2s[threadIdx.x] = b2[threadIdx.x];
    __syncthreads();

    int r = blockIdx.x * 64 + threadIdx.x;
    if (r >= BSZ * KK) return;
    int b = r / KK;
    int node = krig_idx[r];
    const float4* yrow = reinterpret_cast<const float4*>(y + (size_t)(b * NN + node) * SS);

    // load the whole row into registers (24 float4 = 96 VGPR, statically indexed)
    float4 sv[SS / 4];
#pragma unroll
    for (int s4 = 0; s4 < SS / 4; ++s4) sv[s4] = yrow[s4];

    // h = smp @ W1 + b1
    float h[HIDN];
#pragma unroll
    for (int j = 0; j < HIDN; ++j) h[j] = b1s[j];
#pragma unroll
    for (int s4 = 0; s4 < SS / 4; ++s4) {
        float vv[4] = {sv[s4].x, sv[s4].y, sv[s4].z, sv[s4].w};
        const float4* wbase = &w1s[s4 * 4 * (HIDN / 4)];
#pragma unroll
        for (int q = 0; q < 4; ++q) {
#pragma unroll
            for (int j4 = 0; j4 < HIDN / 4; ++j4) {
                float4 w = wbase[q * (HIDN / 4) + j4];
                h[j4 * 4 + 0] += vv[q] * w.x;
                h[j4 * 4 + 1] += vv[q] * w.y;
                h[j4 * 4 + 2] += vv[q] * w.z;
                h[j4 * 4 + 3] += vv[q] * w.w;
            }
        }
    }
    // logits + gumbel; gate is exactly {0,1} (straight-through: value == y_hard)
    float l0 = b2s[0], l1 = b2s[1];
#pragma unroll
    for (int j = 0; j < HIDN; ++j) {
        float hr = fmaxf(h[j], 0.0f);
        l0 += hr * w2s[j * 2 + 0];
        l1 += hr * w2s[j * 2 + 1];
    }
    float g0 = gumbel[r * 2 + 0], g1 = gumbel[r * 2 + 1];
    float gb1 = (l1 + g1 > l0 + g0) ? 1.0f : 0.0f;

    // out[dst] = gb1 * mask * smp (smp from registers)
    const float4* mrow = reinterpret_cast<const float4*>(mask + (size_t)r * SS);
    float4* orow = reinterpret_cast<float4*>(out + (size_t)(offs[b] + node) * SS);
#pragma unroll
    for (int s4 = 0; s4 < SS / 4; ++s4) {
        float4 m = mrow[s4];
        float4 o;
        o.x = gb1 * m.x * sv[s4].x;
        o.y = gb1 * m.y * sv[s4].y;
        o.z = gb1 * m.z * sv[s4].z;
        o.w = gb1 * m.w * sv[s4].w;
        orow[s4] = o;
    }
}

extern "C" void kernel_launch(void* const* d_in, const int* in_sizes, int n_in,
                              void* d_out, int out_size, void* d_ws, size_t ws_size,
                              hipStream_t stream) {
    const float* x      = (const float*)d_in[0];
    const float* y      = (const float*)d_in[1];
    const float* W1     = (const float*)d_in[2];
    const float* b1     = (const float*)d_in[3];
    const float* W2     = (const float*)d_in[4];
    const float* b2     = (const float*)d_in[5];
    const float* mask   = (const float*)d_in[6];
    const float* gumbel = (const float*)d_in[7];
    const int* krig_idx = (const int*)d_in[8];
    const int* idx_of_node = (const int*)d_in[9];
    float* out = (float*)d_out;
    int* offs = (int*)d_ws;

    offs_kernel<<<1, BSZ, 0, stream>>>(idx_of_node, offs);

    // bulk copy x -> out via the runtime's tuned blit (~85% of HBM peak)
    hipMemcpyAsync(out, x, (size_t)BSZ * NN * SS * sizeof(float),
                   hipMemcpyDeviceToDevice, stream);

    int rows = BSZ * KK;
    scatter_kernel<<<(rows + 63) / 64, 64, 0, stream>>>(
        y, W1, b1, W2, b2, mask, gumbel, krig_idx, offs, out);
}

// Round 4
// 69.582 us; speedup vs baseline: 1.0841x; 1.0841x over previous
//
#include <hip/hip_runtime.h>

#define BSZ 512
#define NN  500
#define KK  100
#define SS  96
#define HIDN 32
#define ROWS (BSZ * NN)       // 256000 output rows
#define NF4  (ROWS * SS / 4)  // 6,144,000 float4 elements
#define F4PR (SS / 4)         // 24 float4 per row

typedef float vf4 __attribute__((ext_vector_type(4)));  // nontemporal-compatible

// ---------------- kernel 1: exclusive prefix sum of idx_of_node ----------------
__global__ __launch_bounds__(BSZ) void offs_kernel(const int* __restrict__ idx_of_node,
                                                   int* __restrict__ offs) {
    __shared__ int buf[BSZ];
    int t = threadIdx.x;
    int v = idx_of_node[t];
    buf[t] = v;
    __syncthreads();
    int acc = v;
    for (int d = 1; d < BSZ; d <<= 1) {
        int add = (t >= d) ? buf[t - d] : 0;
        __syncthreads();
        acc += add;
        buf[t] = acc;
        __syncthreads();
    }
    offs[t] = acc - v;  // exclusive prefix
}

// ---------------- kernel 2: gather -> MLP -> gate; record flag+gate ----------------
__global__ __launch_bounds__(256) void gate_kernel(
    const float* __restrict__ y, const float* __restrict__ W1,
    const float* __restrict__ b1, const float* __restrict__ W2,
    const float* __restrict__ b2, const float* __restrict__ gumbel,
    const int* __restrict__ krig_idx, const int* __restrict__ offs,
    int* __restrict__ flag, float* __restrict__ gate) {
    __shared__ float4 w1s[SS * HIDN / 4];  // 12 KB, row-major [s][j]
    __shared__ float b1s[HIDN];
    __shared__ float w2s[HIDN * 2];
    __shared__ float b2s[2];
    for (int i = threadIdx.x; i < SS * HIDN / 4; i += 256)
        w1s[i] = reinterpret_cast<const float4*>(W1)[i];
    if (threadIdx.x < HIDN) b1s[threadIdx.x] = b1[threadIdx.x];
    if (threadIdx.x < 2 * HIDN) w2s[threadIdx.x] = W2[threadIdx.x];
    if (threadIdx.x < 2) b2s[threadIdx.x] = b2[threadIdx.x];
    __syncthreads();

    int r = blockIdx.x * 256 + threadIdx.x;
    if (r >= BSZ * KK) return;
    int b = r / KK;
    int node = krig_idx[r];
    const float4* yrow = reinterpret_cast<const float4*>(y + (size_t)(b * NN + node) * SS);

    float h[HIDN];
#pragma unroll
    for (int j = 0; j < HIDN; ++j) h[j] = b1s[j];
#pragma unroll
    for (int s4 = 0; s4 < F4PR; ++s4) {
        float4 v = yrow[s4];
        float vv[4] = {v.x, v.y, v.z, v.w};
        const float4* wbase = &w1s[s4 * 4 * (HIDN / 4)];
#pragma unroll
        for (int q = 0; q < 4; ++q) {
#pragma unroll
            for (int j4 = 0; j4 < HIDN / 4; ++j4) {
                float4 w = wbase[q * (HIDN / 4) + j4];
                h[j4 * 4 + 0] += vv[q] * w.x;
                h[j4 * 4 + 1] += vv[q] * w.y;
                h[j4 * 4 + 2] += vv[q] * w.z;
                h[j4 * 4 + 3] += vv[q] * w.w;
            }
        }
    }
    float l0 = b2s[0], l1 = b2s[1];
#pragma unroll
    for (int j = 0; j < HIDN; ++j) {
        float hr = fmaxf(h[j], 0.0f);
        l0 += hr * w2s[j * 2 + 0];
        l1 += hr * w2s[j * 2 + 1];
    }
    float g0 = gumbel[r * 2 + 0], g1 = gumbel[r * 2 + 1];
    // straight-through hard gumbel: forward value is exactly one-hot {0,1}
    gate[r] = (l1 + g1 > l0 + g0) ? 1.0f : 0.0f;
    flag[offs[b] + node] = r;
}

// ---------------- kernel 3: fused copy / masked-val write (single output pass) ----
__global__ __launch_bounds__(256) void fuse_kernel(
    const vf4* __restrict__ x4, const vf4* __restrict__ y4,
    const vf4* __restrict__ mask4, const float* __restrict__ gate,
    const int* __restrict__ flag, const int* __restrict__ krig_idx,
    vf4* __restrict__ out4) {
    int idx = blockIdx.x * 256 + threadIdx.x;
    int stride = gridDim.x * 256;
    for (; idx < NF4; idx += stride) {
        int row = idx / F4PR;           // magic-mul
        int c = idx - row * F4PR;
        int r = flag[row];
        vf4 o;
        if (r < 0) {
            o = __builtin_nontemporal_load(x4 + idx);  // streaming copy path
        } else {
            int b = r / KK;
            int node = krig_idx[r];
            float g = gate[r];
            vf4 m = mask4[r * F4PR + c];
            vf4 v = y4[(b * NN + node) * F4PR + c];
            o = g * m * v;
        }
        __builtin_nontemporal_store(o, out4 + idx);  // avoid L2/L3 alloc on store
    }
}

extern "C" void kernel_launch(void* const* d_in, const int* in_sizes, int n_in,
                              void* d_out, int out_size, void* d_ws, size_t ws_size,
                              hipStream_t stream) {
    const float* x      = (const float*)d_in[0];
    const float* y      = (const float*)d_in[1];
    const float* W1     = (const float*)d_in[2];
    const float* b1     = (const float*)d_in[3];
    const float* W2     = (const float*)d_in[4];
    const float* b2     = (const float*)d_in[5];
    const float* mask   = (const float*)d_in[6];
    const float* gumbel = (const float*)d_in[7];
    const int* krig_idx = (const int*)d_in[8];
    const int* idx_of_node = (const int*)d_in[9];
    float* out = (float*)d_out;

    int* offs = (int*)d_ws;                       // 512 ints
    int* flag = offs + BSZ;                       // 256000 ints
    float* gate = (float*)(flag + ROWS);          // 51200 floats

    offs_kernel<<<1, BSZ, 0, stream>>>(idx_of_node, offs);
    (void)hipMemsetAsync(flag, 0xFF, (size_t)ROWS * sizeof(int), stream);  // all -1

    int rows = BSZ * KK;
    gate_kernel<<<(rows + 255) / 256, 256, 0, stream>>>(
        y, W1, b1, W2, b2, gumbel, krig_idx, offs, flag, gate);

    fuse_kernel<<<8192, 256, 0, stream>>>(
        reinterpret_cast<const vf4*>(x), reinterpret_cast<const vf4*>(y),
        reinterpret_cast<const vf4*>(mask), gate, flag, krig_idx,
        reinterpret_cast<vf4*>(out));
}

// Round 5
// 66.971 us; speedup vs baseline: 1.1264x; 1.0390x over previous
//
#include <hip/hip_runtime.h>

#define BSZ 512
#define NN  500
#define KK  100
#define SS  96
#define HIDN 32
#define ROWS (BSZ * NN)       // 256000 output rows
#define NF4  (ROWS * SS / 4)  // 6,144,000 float4 elements
#define F4PR (SS / 4)         // 24 float4 per row

typedef float vf4 __attribute__((ext_vector_type(4)));  // nontemporal-compatible

// ------- kernel 1: prefix-sum of idx_of_node (block 0) + flag clear (all blocks) ----
// Replaces hipMemsetAsync: rocclr's small-fill ran at 18.9 GB/s (55 us for 1 MB!).
__global__ __launch_bounds__(512) void prep_kernel(const int* __restrict__ idx_of_node,
                                                   int* __restrict__ offs,
                                                   int* __restrict__ flag) {
    if (blockIdx.x == 0) {
        __shared__ int buf[BSZ];
        int t = threadIdx.x;
        int v = idx_of_node[t];
        buf[t] = v;
        __syncthreads();
        int acc = v;
        for (int d = 1; d < BSZ; d <<= 1) {
            int add = (t >= d) ? buf[t - d] : 0;
            __syncthreads();
            acc += add;
            buf[t] = acc;
            __syncthreads();
        }
        offs[t] = acc - v;  // exclusive prefix
    }
    // all blocks: clear flag to -1 (int4, 64000 elements)
    int4* f4 = reinterpret_cast<int4*>(flag);
    int n4 = ROWS / 4;
    for (int i = blockIdx.x * 512 + threadIdx.x; i < n4; i += gridDim.x * 512)
        f4[i] = make_int4(-1, -1, -1, -1);
}

// ---------------- kernel 2: gather -> MLP -> gate; record flag+gate ----------------
__global__ __launch_bounds__(256) void gate_kernel(
    const float* __restrict__ y, const float* __restrict__ W1,
    const float* __restrict__ b1, const float* __restrict__ W2,
    const float* __restrict__ b2, const float* __restrict__ gumbel,
    const int* __restrict__ krig_idx, const int* __restrict__ offs,
    int* __restrict__ flag, float* __restrict__ gate) {
    __shared__ float4 w1s[SS * HIDN / 4];  // 12 KB, row-major [s][j]
    __shared__ float b1s[HIDN];
    __shared__ float w2s[HIDN * 2];
    __shared__ float b2s[2];
    for (int i = threadIdx.x; i < SS * HIDN / 4; i += 256)
        w1s[i] = reinterpret_cast<const float4*>(W1)[i];
    if (threadIdx.x < HIDN) b1s[threadIdx.x] = b1[threadIdx.x];
    if (threadIdx.x < 2 * HIDN) w2s[threadIdx.x] = W2[threadIdx.x];
    if (threadIdx.x < 2) b2s[threadIdx.x] = b2[threadIdx.x];
    __syncthreads();

    int r = blockIdx.x * 256 + threadIdx.x;
    if (r >= BSZ * KK) return;
    int b = r / KK;
    int node = krig_idx[r];
    const float4* yrow = reinterpret_cast<const float4*>(y + (size_t)(b * NN + node) * SS);

    float h[HIDN];
#pragma unroll
    for (int j = 0; j < HIDN; ++j) h[j] = b1s[j];
#pragma unroll
    for (int s4 = 0; s4 < F4PR; ++s4) {
        float4 v = yrow[s4];
        float vv[4] = {v.x, v.y, v.z, v.w};
        const float4* wbase = &w1s[s4 * 4 * (HIDN / 4)];
#pragma unroll
        for (int q = 0; q < 4; ++q) {
#pragma unroll
            for (int j4 = 0; j4 < HIDN / 4; ++j4) {
                float4 w = wbase[q * (HIDN / 4) + j4];
                h[j4 * 4 + 0] += vv[q] * w.x;
                h[j4 * 4 + 1] += vv[q] * w.y;
                h[j4 * 4 + 2] += vv[q] * w.z;
                h[j4 * 4 + 3] += vv[q] * w.w;
            }
        }
    }
    float l0 = b2s[0], l1 = b2s[1];
#pragma unroll
    for (int j = 0; j < HIDN; ++j) {
        float hr = fmaxf(h[j], 0.0f);
        l0 += hr * w2s[j * 2 + 0];
        l1 += hr * w2s[j * 2 + 1];
    }
    float g0 = gumbel[r * 2 + 0], g1 = gumbel[r * 2 + 1];
    // straight-through hard gumbel: forward value is exactly one-hot {0,1}
    gate[r] = (l1 + g1 > l0 + g0) ? 1.0f : 0.0f;
    flag[offs[b] + node] = r;
}

// ---------------- kernel 3: fused copy / masked-val write (single output pass) ----
__global__ __launch_bounds__(256) void fuse_kernel(
    const vf4* __restrict__ x4, const vf4* __restrict__ y4,
    const vf4* __restrict__ mask4, const float* __restrict__ gate,
    const int* __restrict__ flag, const int* __restrict__ krig_idx,
    vf4* __restrict__ out4) {
    int idx = blockIdx.x * 256 + threadIdx.x;
    int stride = gridDim.x * 256;
    for (; idx < NF4; idx += stride) {
        int row = idx / F4PR;           // magic-mul
        int c = idx - row * F4PR;
        int r = flag[row];
        vf4 o;
        if (r < 0) {
            o = __builtin_nontemporal_load(x4 + idx);  // streaming copy path
        } else {
            int b = r / KK;
            int node = krig_idx[r];
            float g = gate[r];
            vf4 m = mask4[r * F4PR + c];
            vf4 v = y4[(b * NN + node) * F4PR + c];
            o = g * m * v;
        }
        __builtin_nontemporal_store(o, out4 + idx);  // avoid L2/L3 alloc on store
    }
}

extern "C" void kernel_launch(void* const* d_in, const int* in_sizes, int n_in,
                              void* d_out, int out_size, void* d_ws, size_t ws_size,
                              hipStream_t stream) {
    const float* x      = (const float*)d_in[0];
    const float* y      = (const float*)d_in[1];
    const float* W1     = (const float*)d_in[2];
    const float* b1     = (const float*)d_in[3];
    const float* W2     = (const float*)d_in[4];
    const float* b2     = (const float*)d_in[5];
    const float* mask   = (const float*)d_in[6];
    const float* gumbel = (const float*)d_in[7];
    const int* krig_idx = (const int*)d_in[8];
    const int* idx_of_node = (const int*)d_in[9];
    float* out = (float*)d_out;

    int* offs = (int*)d_ws;                       // 512 ints
    int* flag = offs + BSZ;                       // 256000 ints
    float* gate = (float*)(flag + ROWS);          // 51200 floats

    prep_kernel<<<128, 512, 0, stream>>>(idx_of_node, offs, flag);

    int rows = BSZ * KK;
    gate_kernel<<<(rows + 255) / 256, 256, 0, stream>>>(
        y, W1, b1, W2, b2, gumbel, krig_idx, offs, flag, gate);

    fuse_kernel<<<8192, 256, 0, stream>>>(
        reinterpret_cast<const vf4*>(x), reinterpret_cast<const vf4*>(y),
        reinterpret_cast<const vf4*>(mask), gate, flag, krig_idx,
        reinterpret_cast<vf4*>(out));
}